// Round 17
// baseline (296.662 us; speedup 1.0000x reference)
//
#include <hip/hip_runtime.h>

typedef __attribute__((ext_vector_type(8))) __bf16 bf16x8;
typedef __attribute__((ext_vector_type(4))) float floatx4;

#define WS_BIAS  131072   // 16384 f32 : cpb bias [h][n][m]
#define WS_SCALE 196608   // 4 f32     : exp(min(logit_scale, log 100))
#define WS_TBL   196640   // 900 f32   : cpb table (225 x 4)
#define WS_ETAB  262144   // 4.19M bf16: E[wm][h][n][m] = exp(bias+mask), 8 MB

static __device__ __forceinline__ unsigned short f2bf_u(float f) {
  union { __bf16 b; unsigned short u; } cv; cv.b = (__bf16)f; return cv.u;
}
static __device__ __forceinline__ unsigned pkbf(float lo, float hi) {
  union { __bf16 b[2]; unsigned u; } cv; cv.b[0] = (__bf16)lo; cv.b[1] = (__bf16)hi; return cv.u;
}
static __device__ __forceinline__ float bfu_lo(unsigned u) { return __uint_as_float(u << 16); }
static __device__ __forceinline__ float bfu_hi(unsigned u) { return __uint_as_float(u & 0xffff0000u); }

// ---- prep: fp32 weights -> bf16 in ws; logit scale ----
__global__ void k_prep_weights(const float* __restrict__ qkv_w,
                               const float* __restrict__ proj_w,
                               const float* __restrict__ logit_scale,
                               unsigned short* __restrict__ wsQ,
                               float* __restrict__ wsScale)
{
  int t = blockIdx.x * 256 + threadIdx.x;   // 0..16383
  int i4 = t * 4;
  float4 v;
  if (i4 < 49152) v = *reinterpret_cast<const float4*>(qkv_w + i4);
  else            v = *reinterpret_cast<const float4*>(proj_w + (i4 - 49152));
  ushort4 pk;
  pk.x = f2bf_u(v.x); pk.y = f2bf_u(v.y); pk.z = f2bf_u(v.z); pk.w = f2bf_u(v.w);
  *reinterpret_cast<ushort4*>(wsQ + i4) = pk;
  if (t < 4) wsScale[t] = expf(fminf(logit_scale[t], 4.6051702f));
}

// ---- prep: CPB MLP table (225 x 4), one block per table row ----
__global__ void k_cpb_table(const float* __restrict__ w1, const float* __restrict__ b1,
                            const float* __restrict__ w2, float* __restrict__ tbl)
{
  __shared__ float red[256][4];
  int t = blockIdx.x;                  // 0..224
  int i = t / 15, j = t % 15;
  float c0 = 8.f * (float)(i - 7) / 7.f;
  float c1 = 8.f * (float)(j - 7) / 7.f;
  c0 = copysignf(log2f(fabsf(c0) + 1.f) / 3.f, c0);
  c1 = copysignf(log2f(fabsf(c1) + 1.f) / 3.f, c1);
  float a0 = 0.f, a1 = 0.f, a2 = 0.f, a3 = 0.f;
  for (int k = threadIdx.x; k < 512; k += 256) {
    float hd = fmaxf(c0 * w1[2*k] + c1 * w1[2*k+1] + b1[k], 0.f);
    a0 += hd * w2[k]; a1 += hd * w2[512+k]; a2 += hd * w2[1024+k]; a3 += hd * w2[1536+k];
  }
  red[threadIdx.x][0]=a0; red[threadIdx.x][1]=a1; red[threadIdx.x][2]=a2; red[threadIdx.x][3]=a3;
  __syncthreads();
  for (int s = 128; s > 0; s >>= 1) {
    if (threadIdx.x < (unsigned)s) {
      red[threadIdx.x][0] += red[threadIdx.x+s][0];
      red[threadIdx.x][1] += red[threadIdx.x+s][1];
      red[threadIdx.x][2] += red[threadIdx.x+s][2];
      red[threadIdx.x][3] += red[threadIdx.x+s][3];
    }
    __syncthreads();
  }
  if (threadIdx.x < 4) tbl[t*4 + threadIdx.x] = red[0][threadIdx.x];
}

// ---- prep: bias[h][n][m] = 16*sigmoid(tbl[rel(n,m)][h]) ----
__global__ void k_cpb_bias(const float* __restrict__ tbl, float* __restrict__ biasT)
{
  int idx = blockIdx.x * 256 + threadIdx.x;   // 0..16383
  int hh = idx >> 12, n = (idx >> 6) & 63, m = idx & 63;
  int rel = ((n >> 3) - (m >> 3) + 7) * 15 + ((n & 7) - (m & 7) + 7);
  float bv = tbl[rel * 4 + hh];
  biasT[idx] = 16.f / (1.f + expf(-bv));
}

// ---- prep: E[wm][h][n][m] = exp(bias+mask) in bf16 (8 MB) ----
__global__ void k_exp_table(const float* __restrict__ biasT, const float* __restrict__ mask,
                            unsigned short* __restrict__ E)
{
  int idx4 = (blockIdx.x * 256 + threadIdx.x) * 4;
  int wm  = idx4 >> 14;
  int rem = idx4 & 16383;
  int hh  = rem >> 12;
  int nm  = rem & 4095;
  float4 mv = *reinterpret_cast<const float4*>(mask + (wm << 12) + nm);
  float4 bv = *reinterpret_cast<const float4*>(biasT + (hh << 12) + nm);
  ushort4 o;
  o.x = f2bf_u(expf(bv.x + mv.x));
  o.y = f2bf_u(expf(bv.y + mv.y));
  o.z = f2bf_u(expf(bv.z + mv.z));
  o.w = f2bf_u(expf(bv.w + mv.w));
  *reinterpret_cast<ushort4*>(E + idx4) = o;
}

// ---- main fused kernel: paired windows, transient weights (R16) +
// merged q/k sub-GEMM sharing one xf read-set (saves 16 ds_read_b128 +
// addressing per window) + wv loads issued BEFORE staging (latency hidden
// under 16 global loads + LDS writes + barrier). No weight array survives
// its phase; all phase peaks <= ~210 of the 256-total unified budget.
__global__ __launch_bounds__(256, 2) void k_wmsa(
    const float* __restrict__ x,
    const unsigned short* __restrict__ wqkv, const unsigned short* __restrict__ wproj,
    const float* __restrict__ q_bias, const float* __restrict__ v_bias,
    const unsigned short* __restrict__ Etab, const float* __restrict__ scale4,
    const float* __restrict__ proj_b, float* __restrict__ out)
{
  __shared__ char s_x[64 * 256];     // 16KB: x bf16 swizzled; later O [n][c] bf16
  __shared__ char s_qk[4][8192];     // 32KB: per head q[64][32]+k[64][32]; later P[64][64]
  __shared__ char s_vT[4][4096];     // 16KB: per head vT[32][64] bf16, swz (d&7)<<4

  const int blk  = blockIdx.x;
  const int tid  = threadIdx.x;
  const int lane = tid & 63;
  const int h    = tid >> 6;
  const int l15  = lane & 15;
  const int lh   = lane >> 4;
  const int swq  = ((l15 ^ (l15 >> 2)) & 3) << 4;  // q/k row swizzle (row = 16t+l15)
  const int swp  = (l15 & 7) << 4;                 // P / vT row swizzle
  const floatx4 zf4 = {0.f, 0.f, 0.f, 0.f};

  floatx4 qb0 = *reinterpret_cast<const floatx4*>(q_bias + h * 32 + lh * 4);
  floatx4 qb1 = *reinterpret_cast<const floatx4*>(q_bias + h * 32 + 16 + lh * 4);
  const float vb0 = v_bias[h * 32 + l15], vb1 = v_bias[h * 32 + 16 + l15];
  const float sc  = scale4[h] * 1.44269504f;   // fold log2e into q scale
  const float pb0 = proj_b[h * 32 + l15], pb1 = proj_b[h * 32 + 16 + l15];
  const unsigned short* Eh = Etab + ((size_t)((blk & 255) * 4 + h)) * 4096;

  // ---- E-table frags: per-block constant, hoisted across both windows ----
  uint2 e[4][4];   // [tn][tm]: 4 bf16 each (n=tn*16+l15, m=tm*16+lh*4..+3)
  #pragma unroll
  for (int tn = 0; tn < 4; ++tn)
    #pragma unroll
    for (int tm = 0; tm < 4; ++tm)
      e[tn][tm] = *reinterpret_cast<const uint2*>(
          Eh + (tn * 16 + l15) * 64 + tm * 16 + lh * 4);

  #pragma unroll
  for (int wi = 0; wi < 2; ++wi) {
    const size_t b = (size_t)blk + (size_t)wi * 4096;

    // ---- wv loads issued BEFORE staging (hidden under stage + barrier) ----
    bf16x8 wv[4][2];
    #pragma unroll
    for (int kk = 0; kk < 4; ++kk)
      #pragma unroll
      for (int ft = 0; ft < 2; ++ft)
        wv[kk][ft] = *reinterpret_cast<const bf16x8*>(
            wqkv + (size_t)(256 + h * 32 + ft * 16 + l15) * 128 + kk * 32 + lh * 8);

    if (wi) __syncthreads();   // prev proj done reading s_x before restage

    // ---- Phase 0: stage x tile -> bf16 swizzled LDS ----
    {
      const float* xb = x + b * 8192;
      int r = tid >> 2;
      #pragma unroll
      for (int cc = 0; cc < 8; ++cc) {
        int c = (tid & 3) + cc * 4;
        float4 v = reinterpret_cast<const float4*>(xb)[r * 32 + c];
        uint2 w; w.x = pkbf(v.x, v.y); w.y = pkbf(v.z, v.w);
        *reinterpret_cast<uint2*>(s_x + r * 256 + ((c * 8) ^ ((r & 7) << 4))) = w;
      }
    }
    __syncthreads();

    // ---- Phase 1a: v = x @ Wv^T (wv dies here) ----
    {
      floatx4 vacc[4][2];
      #pragma unroll
      for (int mt = 0; mt < 4; ++mt) { vacc[mt][0] = zf4; vacc[mt][1] = zf4; }
      #pragma unroll
      for (int kk = 0; kk < 4; ++kk) {
        bf16x8 xf[4];
        #pragma unroll
        for (int tt = 0; tt < 4; ++tt) {
          int row = tt * 16 + l15;
          xf[tt] = *reinterpret_cast<const bf16x8*>(
              s_x + row * 256 + (((kk * 32 + lh * 8) * 2) ^ ((row & 7) << 4)));
        }
        #pragma unroll
        for (int ft = 0; ft < 2; ++ft)
          #pragma unroll
          for (int mt = 0; mt < 4; ++mt)
            vacc[mt][ft] = __builtin_amdgcn_mfma_f32_16x16x32_bf16(xf[mt], wv[kk][ft], vacc[mt][ft], 0, 0, 0);
      }
      // v bias; vT[d][m] packed b64 writes (wave-private)
      char* sv = s_vT[h];
      #pragma unroll
      for (int mt = 0; mt < 4; ++mt) {
        #pragma unroll
        for (int ft = 0; ft < 2; ++ft) {
          float vb = ft ? vb1 : vb0;
          int d = ft * 16 + l15;
          uint2 w;
          w.x = pkbf(vacc[mt][ft][0] + vb, vacc[mt][ft][1] + vb);
          w.y = pkbf(vacc[mt][ft][2] + vb, vacc[mt][ft][3] + vb);
          *reinterpret_cast<uint2*>(sv + d * 128 + (((mt * 16 + lh * 4) * 2) ^ swp)) = w;
        }
      }
    }

    // ---- Phase 1bc (merged): q^T,k^T = W_qk @ x^T, one xf read-set ----
    bf16x8 qf[4], kf[4];
    {
      bf16x8 wqk[4][4];   // [kk][ff]: ff 0,1 = q halves; 2,3 = k halves
      #pragma unroll
      for (int kk = 0; kk < 4; ++kk)
        #pragma unroll
        for (int ff = 0; ff < 4; ++ff) {
          int fb = (ff < 2) ? (h * 32 + ff * 16) : (128 + h * 32 + (ff - 2) * 16);
          wqk[kk][ff] = *reinterpret_cast<const bf16x8*>(
              wqkv + (size_t)(fb + l15) * 128 + kk * 32 + lh * 8);
        }
      floatx4 qacc[2][4], kacc[2][4];
      #pragma unroll
      for (int ff = 0; ff < 2; ++ff)
        #pragma unroll
        for (int tt = 0; tt < 4; ++tt) { qacc[ff][tt] = zf4; kacc[ff][tt] = zf4; }
      #pragma unroll
      for (int kk = 0; kk < 4; ++kk) {
        bf16x8 xf[4];
        #pragma unroll
        for (int tt = 0; tt < 4; ++tt) {
          int row = tt * 16 + l15;
          xf[tt] = *reinterpret_cast<const bf16x8*>(
              s_x + row * 256 + (((kk * 32 + lh * 8) * 2) ^ ((row & 7) << 4)));
        }
        #pragma unroll
        for (int ff = 0; ff < 2; ++ff)
          #pragma unroll
          for (int tt = 0; tt < 4; ++tt) {
            qacc[ff][tt] = __builtin_amdgcn_mfma_f32_16x16x32_bf16(wqk[kk][ff],     xf[tt], qacc[ff][tt], 0, 0, 0);
            kacc[ff][tt] = __builtin_amdgcn_mfma_f32_16x16x32_bf16(wqk[kk][2 + ff], xf[tt], kacc[ff][tt], 0, 0, 0);
          }
      }
      // q bias + norm (log2e folded); k norm
      #pragma unroll
      for (int tt = 0; tt < 4; ++tt) {
        #pragma unroll
        for (int r = 0; r < 4; ++r) { qacc[0][tt][r] += qb0[r]; qacc[1][tt][r] += qb1[r]; }
        float sq = 0.f, sk = 0.f;
        #pragma unroll
        for (int r = 0; r < 4; ++r) {
          sq += qacc[0][tt][r] * qacc[0][tt][r] + qacc[1][tt][r] * qacc[1][tt][r];
          sk += kacc[0][tt][r] * kacc[0][tt][r] + kacc[1][tt][r] * kacc[1][tt][r];
        }
        sq += __shfl_xor(sq, 16); sq += __shfl_xor(sq, 32);
        sk += __shfl_xor(sk, 16); sk += __shfl_xor(sk, 32);
        float rq = sc / fmaxf(sqrtf(sq), 1e-12f);
        float rk = 1.f / fmaxf(sqrtf(sk), 1e-12f);
        #pragma unroll
        for (int r = 0; r < 4; ++r) {
          qacc[0][tt][r] *= rq; qacc[1][tt][r] *= rq;
          kacc[0][tt][r] *= rk; kacc[1][tt][r] *= rk;
        }
      }
      // write q,k tiles (64B rows, swz swq), packed b64; read back frags
      char* sq = s_qk[h];
      #pragma unroll
      for (int tt = 0; tt < 4; ++tt) {
        int row = 16 * tt + l15;
        #pragma unroll
        for (int ff = 0; ff < 2; ++ff) {
          uint2 wq_, wk_;
          wq_.x = pkbf(qacc[ff][tt][0], qacc[ff][tt][1]);
          wq_.y = pkbf(qacc[ff][tt][2], qacc[ff][tt][3]);
          wk_.x = pkbf(kacc[ff][tt][0], kacc[ff][tt][1]);
          wk_.y = pkbf(kacc[ff][tt][2], kacc[ff][tt][3]);
          int colb = (ff * 32 + lh * 8) ^ swq;
          *reinterpret_cast<uint2*>(sq + row * 64 + colb)        = wq_;
          *reinterpret_cast<uint2*>(sq + 4096 + row * 64 + colb) = wk_;
        }
      }
      #pragma unroll
      for (int tt = 0; tt < 4; ++tt) {
        int row = 16 * tt + l15;
        qf[tt] = *reinterpret_cast<const bf16x8*>(sq + row * 64 + ((lh * 16) ^ swq));
        kf[tt] = *reinterpret_cast<const bf16x8*>(sq + 4096 + row * 64 + ((lh * 16) ^ swq));
      }
    }

    // ---- Phase 2+3 fused: S^T, exp2*E, col sums, P->LDS ----
    floatx4 rs;
    {
      char* sp = s_qk[h];   // P overwrites q/k (qf/kf already in regs)
      #pragma unroll
      for (int tn = 0; tn < 4; ++tn) {
        floatx4 sacc[4];
        #pragma unroll
        for (int tm = 0; tm < 4; ++tm)
          sacc[tm] = __builtin_amdgcn_mfma_f32_16x16x32_bf16(kf[tm], qf[tn], zf4, 0, 0, 0);
        float sum = 0.f;
        uint2 pw[4];
        #pragma unroll
        for (int tm = 0; tm < 4; ++tm) {
          uint2 eu = e[tn][tm];
          float e0 = exp2f(sacc[tm][0]) * bfu_lo(eu.x);
          float e1 = exp2f(sacc[tm][1]) * bfu_hi(eu.x);
          float e2 = exp2f(sacc[tm][2]) * bfu_lo(eu.y);
          float e3 = exp2f(sacc[tm][3]) * bfu_hi(eu.y);
          sum += (e0 + e1) + (e2 + e3);
          pw[tm].x = pkbf(e0, e1); pw[tm].y = pkbf(e2, e3);
        }
        sum += __shfl_xor(sum, 16); sum += __shfl_xor(sum, 32);
        rs[tn] = 1.f / sum;
        int prow = 16 * tn + l15;
        #pragma unroll
        for (int tm = 0; tm < 4; ++tm)
          *reinterpret_cast<uint2*>(sp + prow * 128 + ((tm * 32 + lh * 8) ^ swp)) = pw[tm];
      }
    }

    // ---- Phase 4: O^T = V^T @ P^T ----
    floatx4 oacc[2][4];
    #pragma unroll
    for (int dt = 0; dt < 2; ++dt)
      #pragma unroll
      for (int nt = 0; nt < 4; ++nt) oacc[dt][nt] = zf4;
    {
      const char* sv = s_vT[h];
      const char* sp = s_qk[h];
      #pragma unroll
      for (int kk = 0; kk < 2; ++kk) {
        bf16x8 vf[2];
        #pragma unroll
        for (int dt = 0; dt < 2; ++dt)
          vf[dt] = *reinterpret_cast<const bf16x8*>(
              sv + (dt * 16 + l15) * 128 + ((kk * 64 + lh * 16) ^ swp));
        #pragma unroll
        for (int nt = 0; nt < 4; ++nt) {
          bf16x8 pf = *reinterpret_cast<const bf16x8*>(
              sp + (nt * 16 + l15) * 128 + ((kk * 64 + lh * 16) ^ swp));
          #pragma unroll
          for (int dt = 0; dt < 2; ++dt)
            oacc[dt][nt] = __builtin_amdgcn_mfma_f32_16x16x32_bf16(vf[dt], pf, oacc[dt][nt], 0, 0, 0);
        }
      }
    }
    __syncthreads();   // all waves done reading s_x before O overwrites it

    // O (scaled by 1/rowsum) -> s_x as [n][c] bf16
    #pragma unroll
    for (int dt = 0; dt < 2; ++dt) {
      #pragma unroll
      for (int nt = 0; nt < 4; ++nt) {
        int n = nt * 16 + l15;
        uint2 w;
        w.x = pkbf(oacc[dt][nt][0] * rs[nt], oacc[dt][nt][1] * rs[nt]);
        w.y = pkbf(oacc[dt][nt][2] * rs[nt], oacc[dt][nt][3] * rs[nt]);
        *reinterpret_cast<uint2*>(
            s_x + n * 256 + (((h * 32 + dt * 16 + lh * 4) * 2) ^ ((n & 7) << 4))) = w;
      }
    }
    __syncthreads();

    // ---- Phase 5: proj GEMM + bias, fp32 store (wp transient) ----
    {
      bf16x8 wp[4][2];
      #pragma unroll
      for (int kk = 0; kk < 4; ++kk)
        #pragma unroll
        for (int ft = 0; ft < 2; ++ft)
          wp[kk][ft] = *reinterpret_cast<const bf16x8*>(
              wproj + (size_t)(h * 32 + ft * 16 + l15) * 128 + kk * 32 + lh * 8);
      floatx4 pacc[4][2];
      #pragma unroll
      for (int mt = 0; mt < 4; ++mt) { pacc[mt][0] = zf4; pacc[mt][1] = zf4; }
      #pragma unroll
      for (int kk = 0; kk < 4; ++kk) {
        bf16x8 of[4];
        #pragma unroll
        for (int mt = 0; mt < 4; ++mt) {
          int row = mt * 16 + l15;
          of[mt] = *reinterpret_cast<const bf16x8*>(
              s_x + row * 256 + (((kk * 32 + lh * 8) * 2) ^ ((row & 7) << 4)));
        }
        #pragma unroll
        for (int ft = 0; ft < 2; ++ft)
          #pragma unroll
          for (int mt = 0; mt < 4; ++mt)
            pacc[mt][ft] = __builtin_amdgcn_mfma_f32_16x16x32_bf16(of[mt], wp[kk][ft], pacc[mt][ft], 0, 0, 0);
      }
      float* ob = out + b * 8192;
      #pragma unroll
      for (int mt = 0; mt < 4; ++mt)
        #pragma unroll
        for (int r = 0; r < 4; ++r) {
          int n = mt * 16 + lh * 4 + r;
          ob[n * 128 + h * 32 + l15]      = pacc[mt][0][r] + pb0;
          ob[n * 128 + h * 32 + 16 + l15] = pacc[mt][1][r] + pb1;
        }
    }
  }
}

extern "C" void kernel_launch(void* const* d_in, const int* in_sizes, int n_in,
                              void* d_out, int out_size, void* d_ws, size_t ws_size,
                              hipStream_t stream)
{
  const float* x    = (const float*)d_in[0];
  const float* mask = (const float*)d_in[1];
  const float* qkvw = (const float*)d_in[2];
  const float* qb   = (const float*)d_in[3];
  const float* vb   = (const float*)d_in[4];
  const float* ls   = (const float*)d_in[5];
  const float* w1   = (const float*)d_in[6];
  const float* b1   = (const float*)d_in[7];
  const float* w2   = (const float*)d_in[8];
  const float* pw   = (const float*)d_in[9];
  const float* pb   = (const float*)d_in[10];
  float* out = (float*)d_out;
  char* ws = (char*)d_ws;

  unsigned short* wsQ = (unsigned short*)ws;   // qkv bf16 + proj bf16
  float* wsBias  = (float*)(ws + WS_BIAS);
  float* wsScale = (float*)(ws + WS_SCALE);
  float* wsTbl   = (float*)(ws + WS_TBL);
  unsigned short* wsE = (unsigned short*)(ws + WS_ETAB);

  hipLaunchKernelGGL(k_prep_weights, dim3(64), dim3(256), 0, stream, qkvw, pw, ls, wsQ, wsScale);
  hipLaunchKernelGGL(k_cpb_table, dim3(225), dim3(256), 0, stream, w1, b1, w2, wsTbl);
  hipLaunchKernelGGL(k_cpb_bias, dim3(64), dim3(256), 0, stream, wsTbl, wsBias);
  hipLaunchKernelGGL(k_exp_table, dim3(4096), dim3(256), 0, stream, wsBias, mask, wsE);
  hipLaunchKernelGGL(k_wmsa, dim3(4096), dim3(256), 0, stream, x,
                     wsQ, wsQ + 49152, qb, vb, wsE, wsScale, pb, out);
}

// Round 18
// 272.818 us; speedup vs baseline: 1.0874x; 1.0874x over previous
//
#include <hip/hip_runtime.h>

typedef __attribute__((ext_vector_type(8))) __bf16 bf16x8;
typedef __attribute__((ext_vector_type(4))) float floatx4;

#define WS_BIAS  131072   // 16384 f32 : cpb bias [h][n][m]
#define WS_SCALE 196608   // 4 f32     : exp(min(logit_scale, log 100))
#define WS_TBL   196640   // 900 f32   : cpb table (225 x 4)
#define WS_ETAB  262144   // 4.19M bf16: E[wm][h][n][m] = exp(bias+mask), 8 MB

static __device__ __forceinline__ unsigned short f2bf_u(float f) {
  union { __bf16 b; unsigned short u; } cv; cv.b = (__bf16)f; return cv.u;
}
static __device__ __forceinline__ unsigned pkbf(float lo, float hi) {
  union { __bf16 b[2]; unsigned u; } cv; cv.b[0] = (__bf16)lo; cv.b[1] = (__bf16)hi; return cv.u;
}
static __device__ __forceinline__ float bfu_lo(unsigned u) { return __uint_as_float(u << 16); }
static __device__ __forceinline__ float bfu_hi(unsigned u) { return __uint_as_float(u & 0xffff0000u); }

// ---- prep: fp32 weights -> bf16 in ws; logit scale ----
__global__ void k_prep_weights(const float* __restrict__ qkv_w,
                               const float* __restrict__ proj_w,
                               const float* __restrict__ logit_scale,
                               unsigned short* __restrict__ wsQ,
                               float* __restrict__ wsScale)
{
  int t = blockIdx.x * 256 + threadIdx.x;   // 0..16383
  int i4 = t * 4;
  float4 v;
  if (i4 < 49152) v = *reinterpret_cast<const float4*>(qkv_w + i4);
  else            v = *reinterpret_cast<const float4*>(proj_w + (i4 - 49152));
  ushort4 pk;
  pk.x = f2bf_u(v.x); pk.y = f2bf_u(v.y); pk.z = f2bf_u(v.z); pk.w = f2bf_u(v.w);
  *reinterpret_cast<ushort4*>(wsQ + i4) = pk;
  if (t < 4) wsScale[t] = expf(fminf(logit_scale[t], 4.6051702f));
}

// ---- prep: CPB MLP table (225 x 4), one block per table row ----
__global__ void k_cpb_table(const float* __restrict__ w1, const float* __restrict__ b1,
                            const float* __restrict__ w2, float* __restrict__ tbl)
{
  __shared__ float red[256][4];
  int t = blockIdx.x;                  // 0..224
  int i = t / 15, j = t % 15;
  float c0 = 8.f * (float)(i - 7) / 7.f;
  float c1 = 8.f * (float)(j - 7) / 7.f;
  c0 = copysignf(log2f(fabsf(c0) + 1.f) / 3.f, c0);
  c1 = copysignf(log2f(fabsf(c1) + 1.f) / 3.f, c1);
  float a0 = 0.f, a1 = 0.f, a2 = 0.f, a3 = 0.f;
  for (int k = threadIdx.x; k < 512; k += 256) {
    float hd = fmaxf(c0 * w1[2*k] + c1 * w1[2*k+1] + b1[k], 0.f);
    a0 += hd * w2[k]; a1 += hd * w2[512+k]; a2 += hd * w2[1024+k]; a3 += hd * w2[1536+k];
  }
  red[threadIdx.x][0]=a0; red[threadIdx.x][1]=a1; red[threadIdx.x][2]=a2; red[threadIdx.x][3]=a3;
  __syncthreads();
  for (int s = 128; s > 0; s >>= 1) {
    if (threadIdx.x < (unsigned)s) {
      red[threadIdx.x][0] += red[threadIdx.x+s][0];
      red[threadIdx.x][1] += red[threadIdx.x+s][1];
      red[threadIdx.x][2] += red[threadIdx.x+s][2];
      red[threadIdx.x][3] += red[threadIdx.x+s][3];
    }
    __syncthreads();
  }
  if (threadIdx.x < 4) tbl[t*4 + threadIdx.x] = red[0][threadIdx.x];
}

// ---- prep: bias[h][n][m] = 16*sigmoid(tbl[rel(n,m)][h]) ----
__global__ void k_cpb_bias(const float* __restrict__ tbl, float* __restrict__ biasT)
{
  int idx = blockIdx.x * 256 + threadIdx.x;   // 0..16383
  int hh = idx >> 12, n = (idx >> 6) & 63, m = idx & 63;
  int rel = ((n >> 3) - (m >> 3) + 7) * 15 + ((n & 7) - (m & 7) + 7);
  float bv = tbl[rel * 4 + hh];
  biasT[idx] = 16.f / (1.f + expf(-bv));
}

// ---- prep: E[wm][h][n][m] = exp(bias+mask) in bf16 (8 MB) ----
__global__ void k_exp_table(const float* __restrict__ biasT, const float* __restrict__ mask,
                            unsigned short* __restrict__ E)
{
  int idx4 = (blockIdx.x * 256 + threadIdx.x) * 4;
  int wm  = idx4 >> 14;
  int rem = idx4 & 16383;
  int hh  = rem >> 12;
  int nm  = rem & 4095;
  float4 mv = *reinterpret_cast<const float4*>(mask + (wm << 12) + nm);
  float4 bv = *reinterpret_cast<const float4*>(biasT + (hh << 12) + nm);
  ushort4 o;
  o.x = f2bf_u(expf(bv.x + mv.x));
  o.y = f2bf_u(expf(bv.y + mv.y));
  o.z = f2bf_u(expf(bv.z + mv.z));
  o.w = f2bf_u(expf(bv.w + mv.w));
  *reinterpret_cast<ushort4*>(E + idx4) = o;
}

// ---- main fused kernel: R16 (best, 249us) + O routed through s_vT ----
// vT is dead after PV; O (64x32 bf16/head = 4KB) reuses s_vT[h] as [n][32c]
// 64B rows, swq-swizzled. s_x is never overwritten -> top-of-window barrier
// removed (2 barriers/window). Proj reads head kk's O from s_vT[kk].
// Transient weights per phase (R16's proven low-pressure shape; R17's merged
// qk GEMM at VGPR 128 regressed -- pressure, not instruction count, governs).
__global__ __launch_bounds__(256, 2) void k_wmsa(
    const float* __restrict__ x,
    const unsigned short* __restrict__ wqkv, const unsigned short* __restrict__ wproj,
    const float* __restrict__ q_bias, const float* __restrict__ v_bias,
    const unsigned short* __restrict__ Etab, const float* __restrict__ scale4,
    const float* __restrict__ proj_b, float* __restrict__ out)
{
  __shared__ char s_x[64 * 256];     // 16KB: x bf16 swizzled (read-only after stage)
  __shared__ char s_qk[4][8192];     // 32KB: per head q[64][32]+k[64][32]; later P[64][64]
  __shared__ char s_vT[4][4096];     // 16KB: per head vT[32][64]; then O [64][32c]

  const int blk  = blockIdx.x;
  const int tid  = threadIdx.x;
  const int lane = tid & 63;
  const int h    = tid >> 6;
  const int l15  = lane & 15;
  const int lh   = lane >> 4;
  const int swq  = ((l15 ^ (l15 >> 2)) & 3) << 4;  // 64B-row swizzle (rows keyed by l15)
  const int swp  = (l15 & 7) << 4;                 // P / vT row swizzle
  const floatx4 zf4 = {0.f, 0.f, 0.f, 0.f};

  floatx4 qb0 = *reinterpret_cast<const floatx4*>(q_bias + h * 32 + lh * 4);
  floatx4 qb1 = *reinterpret_cast<const floatx4*>(q_bias + h * 32 + 16 + lh * 4);
  const float vb0 = v_bias[h * 32 + l15], vb1 = v_bias[h * 32 + 16 + l15];
  const float sc  = scale4[h] * 1.44269504f;   // fold log2e into q scale
  const float pb0 = proj_b[h * 32 + l15], pb1 = proj_b[h * 32 + 16 + l15];
  const unsigned short* Eh = Etab + ((size_t)((blk & 255) * 4 + h)) * 4096;

  // ---- E-table frags: per-block constant, hoisted across both windows ----
  uint2 e[4][4];   // [tn][tm]: 4 bf16 each (n=tn*16+l15, m=tm*16+lh*4..+3)
  #pragma unroll
  for (int tn = 0; tn < 4; ++tn)
    #pragma unroll
    for (int tm = 0; tm < 4; ++tm)
      e[tn][tm] = *reinterpret_cast<const uint2*>(
          Eh + (tn * 16 + l15) * 64 + tm * 16 + lh * 4);

  #pragma unroll
  for (int wi = 0; wi < 2; ++wi) {
    const size_t b = (size_t)blk + (size_t)wi * 4096;

    // ---- Phase 0: stage x tile -> bf16 swizzled LDS (s_x never overwritten,
    //      and prev window's proj reads only s_vT -> no top barrier needed) ----
    {
      const float* xb = x + b * 8192;
      int r = tid >> 2;
      #pragma unroll
      for (int cc = 0; cc < 8; ++cc) {
        int c = (tid & 3) + cc * 4;
        float4 v = reinterpret_cast<const float4*>(xb)[r * 32 + c];
        uint2 w; w.x = pkbf(v.x, v.y); w.y = pkbf(v.z, v.w);
        *reinterpret_cast<uint2*>(s_x + r * 256 + ((c * 8) ^ ((r & 7) << 4))) = w;
      }
    }
    __syncthreads();   // orders: stage complete AND prev proj's s_vT reads done

    // ---- Phase 1a: v = x @ Wv^T (wv transient) ----
    {
      bf16x8 wv[4][2];
      #pragma unroll
      for (int kk = 0; kk < 4; ++kk)
        #pragma unroll
        for (int ft = 0; ft < 2; ++ft)
          wv[kk][ft] = *reinterpret_cast<const bf16x8*>(
              wqkv + (size_t)(256 + h * 32 + ft * 16 + l15) * 128 + kk * 32 + lh * 8);
      floatx4 vacc[4][2];
      #pragma unroll
      for (int mt = 0; mt < 4; ++mt) { vacc[mt][0] = zf4; vacc[mt][1] = zf4; }
      #pragma unroll
      for (int kk = 0; kk < 4; ++kk) {
        bf16x8 xf[4];
        #pragma unroll
        for (int tt = 0; tt < 4; ++tt) {
          int row = tt * 16 + l15;
          xf[tt] = *reinterpret_cast<const bf16x8*>(
              s_x + row * 256 + (((kk * 32 + lh * 8) * 2) ^ ((row & 7) << 4)));
        }
        #pragma unroll
        for (int ft = 0; ft < 2; ++ft)
          #pragma unroll
          for (int mt = 0; mt < 4; ++mt)
            vacc[mt][ft] = __builtin_amdgcn_mfma_f32_16x16x32_bf16(xf[mt], wv[kk][ft], vacc[mt][ft], 0, 0, 0);
      }
      // v bias; vT[d][m] packed b64 writes (wave-private)
      char* sv = s_vT[h];
      #pragma unroll
      for (int mt = 0; mt < 4; ++mt) {
        #pragma unroll
        for (int ft = 0; ft < 2; ++ft) {
          float vb = ft ? vb1 : vb0;
          int d = ft * 16 + l15;
          uint2 w;
          w.x = pkbf(vacc[mt][ft][0] + vb, vacc[mt][ft][1] + vb);
          w.y = pkbf(vacc[mt][ft][2] + vb, vacc[mt][ft][3] + vb);
          *reinterpret_cast<uint2*>(sv + d * 128 + (((mt * 16 + lh * 4) * 2) ^ swp)) = w;
        }
      }
    }

    // ---- Phase 1b: q^T = Wq @ x^T (wq transient); bias+norm; -> LDS -> qf ----
    bf16x8 qf[4], kf[4];
    {
      bf16x8 wq[4][2];
      #pragma unroll
      for (int kk = 0; kk < 4; ++kk)
        #pragma unroll
        for (int ft = 0; ft < 2; ++ft)
          wq[kk][ft] = *reinterpret_cast<const bf16x8*>(
              wqkv + (size_t)(h * 32 + ft * 16 + l15) * 128 + kk * 32 + lh * 8);
      floatx4 qacc[2][4];
      #pragma unroll
      for (int ff = 0; ff < 2; ++ff)
        #pragma unroll
        for (int tt = 0; tt < 4; ++tt) qacc[ff][tt] = zf4;
      #pragma unroll
      for (int kk = 0; kk < 4; ++kk) {
        bf16x8 xf[4];
        #pragma unroll
        for (int tt = 0; tt < 4; ++tt) {
          int row = tt * 16 + l15;
          xf[tt] = *reinterpret_cast<const bf16x8*>(
              s_x + row * 256 + (((kk * 32 + lh * 8) * 2) ^ ((row & 7) << 4)));
        }
        #pragma unroll
        for (int ff = 0; ff < 2; ++ff)
          #pragma unroll
          for (int tt = 0; tt < 4; ++tt)
            qacc[ff][tt] = __builtin_amdgcn_mfma_f32_16x16x32_bf16(wq[kk][ff], xf[tt], qacc[ff][tt], 0, 0, 0);
      }
      #pragma unroll
      for (int tt = 0; tt < 4; ++tt) {
        #pragma unroll
        for (int r = 0; r < 4; ++r) { qacc[0][tt][r] += qb0[r]; qacc[1][tt][r] += qb1[r]; }
        float sq = 0.f;
        #pragma unroll
        for (int r = 0; r < 4; ++r)
          sq += qacc[0][tt][r] * qacc[0][tt][r] + qacc[1][tt][r] * qacc[1][tt][r];
        sq += __shfl_xor(sq, 16); sq += __shfl_xor(sq, 32);
        float rq = sc / fmaxf(sqrtf(sq), 1e-12f);
        #pragma unroll
        for (int r = 0; r < 4; ++r) { qacc[0][tt][r] *= rq; qacc[1][tt][r] *= rq; }
      }
      char* sq = s_qk[h];
      #pragma unroll
      for (int tt = 0; tt < 4; ++tt) {
        int row = 16 * tt + l15;
        #pragma unroll
        for (int ff = 0; ff < 2; ++ff) {
          uint2 w;
          w.x = pkbf(qacc[ff][tt][0], qacc[ff][tt][1]);
          w.y = pkbf(qacc[ff][tt][2], qacc[ff][tt][3]);
          *reinterpret_cast<uint2*>(sq + row * 64 + ((ff * 32 + lh * 8) ^ swq)) = w;
        }
      }
      #pragma unroll
      for (int tt = 0; tt < 4; ++tt)
        qf[tt] = *reinterpret_cast<const bf16x8*>(sq + (16 * tt + l15) * 64 + ((lh * 16) ^ swq));
    }

    // ---- Phase 1c: k^T = Wk @ x^T (wk transient); norm; -> LDS -> kf ----
    {
      bf16x8 wk[4][2];
      #pragma unroll
      for (int kk = 0; kk < 4; ++kk)
        #pragma unroll
        for (int ft = 0; ft < 2; ++ft)
          wk[kk][ft] = *reinterpret_cast<const bf16x8*>(
              wqkv + (size_t)(128 + h * 32 + ft * 16 + l15) * 128 + kk * 32 + lh * 8);
      floatx4 kacc[2][4];
      #pragma unroll
      for (int ff = 0; ff < 2; ++ff)
        #pragma unroll
        for (int tt = 0; tt < 4; ++tt) kacc[ff][tt] = zf4;
      #pragma unroll
      for (int kk = 0; kk < 4; ++kk) {
        bf16x8 xf[4];
        #pragma unroll
        for (int tt = 0; tt < 4; ++tt) {
          int row = tt * 16 + l15;
          xf[tt] = *reinterpret_cast<const bf16x8*>(
              s_x + row * 256 + (((kk * 32 + lh * 8) * 2) ^ ((row & 7) << 4)));
        }
        #pragma unroll
        for (int ff = 0; ff < 2; ++ff)
          #pragma unroll
          for (int tt = 0; tt < 4; ++tt)
            kacc[ff][tt] = __builtin_amdgcn_mfma_f32_16x16x32_bf16(wk[kk][ff], xf[tt], kacc[ff][tt], 0, 0, 0);
      }
      #pragma unroll
      for (int tt = 0; tt < 4; ++tt) {
        float sk = 0.f;
        #pragma unroll
        for (int r = 0; r < 4; ++r)
          sk += kacc[0][tt][r] * kacc[0][tt][r] + kacc[1][tt][r] * kacc[1][tt][r];
        sk += __shfl_xor(sk, 16); sk += __shfl_xor(sk, 32);
        float rk = 1.f / fmaxf(sqrtf(sk), 1e-12f);
        #pragma unroll
        for (int r = 0; r < 4; ++r) { kacc[0][tt][r] *= rk; kacc[1][tt][r] *= rk; }
      }
      char* sq = s_qk[h];
      #pragma unroll
      for (int tt = 0; tt < 4; ++tt) {
        int row = 16 * tt + l15;
        #pragma unroll
        for (int ff = 0; ff < 2; ++ff) {
          uint2 w;
          w.x = pkbf(kacc[ff][tt][0], kacc[ff][tt][1]);
          w.y = pkbf(kacc[ff][tt][2], kacc[ff][tt][3]);
          *reinterpret_cast<uint2*>(sq + 4096 + row * 64 + ((ff * 32 + lh * 8) ^ swq)) = w;
        }
      }
      #pragma unroll
      for (int tt = 0; tt < 4; ++tt)
        kf[tt] = *reinterpret_cast<const bf16x8*>(
            sq + 4096 + (16 * tt + l15) * 64 + ((lh * 16) ^ swq));
    }

    // ---- Phase 2+3 fused: S^T, exp2*E, col sums, P->LDS ----
    floatx4 rs;
    {
      char* sp = s_qk[h];   // P overwrites q/k (qf/kf already in regs)
      #pragma unroll
      for (int tn = 0; tn < 4; ++tn) {
        floatx4 sacc[4];
        #pragma unroll
        for (int tm = 0; tm < 4; ++tm)
          sacc[tm] = __builtin_amdgcn_mfma_f32_16x16x32_bf16(kf[tm], qf[tn], zf4, 0, 0, 0);
        float sum = 0.f;
        uint2 pw[4];
        #pragma unroll
        for (int tm = 0; tm < 4; ++tm) {
          uint2 eu = e[tn][tm];
          float e0 = exp2f(sacc[tm][0]) * bfu_lo(eu.x);
          float e1 = exp2f(sacc[tm][1]) * bfu_hi(eu.x);
          float e2 = exp2f(sacc[tm][2]) * bfu_lo(eu.y);
          float e3 = exp2f(sacc[tm][3]) * bfu_hi(eu.y);
          sum += (e0 + e1) + (e2 + e3);
          pw[tm].x = pkbf(e0, e1); pw[tm].y = pkbf(e2, e3);
        }
        sum += __shfl_xor(sum, 16); sum += __shfl_xor(sum, 32);
        rs[tn] = 1.f / sum;
        int prow = 16 * tn + l15;
        #pragma unroll
        for (int tm = 0; tm < 4; ++tm)
          *reinterpret_cast<uint2*>(sp + prow * 128 + ((tm * 32 + lh * 8) ^ swp)) = pw[tm];
      }
    }

    // ---- Phase 4: O^T = V^T @ P^T ----
    floatx4 oacc[2][4];
    #pragma unroll
    for (int dt = 0; dt < 2; ++dt)
      #pragma unroll
      for (int nt = 0; nt < 4; ++nt) oacc[dt][nt] = zf4;
    {
      const char* sv = s_vT[h];
      const char* sp = s_qk[h];
      #pragma unroll
      for (int kk = 0; kk < 2; ++kk) {
        bf16x8 vf[2];
        #pragma unroll
        for (int dt = 0; dt < 2; ++dt)
          vf[dt] = *reinterpret_cast<const bf16x8*>(
              sv + (dt * 16 + l15) * 128 + ((kk * 64 + lh * 16) ^ swp));
        #pragma unroll
        for (int nt = 0; nt < 4; ++nt) {
          bf16x8 pf = *reinterpret_cast<const bf16x8*>(
              sp + (nt * 16 + l15) * 128 + ((kk * 64 + lh * 16) ^ swp));
          #pragma unroll
          for (int dt = 0; dt < 2; ++dt)
            oacc[dt][nt] = __builtin_amdgcn_mfma_f32_16x16x32_bf16(vf[dt], pf, oacc[dt][nt], 0, 0, 0);
        }
      }
    }

    // O (scaled) -> s_vT[h] as [n][32c] bf16, 64B rows, swq swizzle
    // (vT dead after PV; in-wave LDS ordering makes this safe without barrier)
    {
      char* sv = s_vT[h];
      #pragma unroll
      for (int dt = 0; dt < 2; ++dt) {
        #pragma unroll
        for (int nt = 0; nt < 4; ++nt) {
          int n = nt * 16 + l15;
          uint2 w;
          w.x = pkbf(oacc[dt][nt][0] * rs[nt], oacc[dt][nt][1] * rs[nt]);
          w.y = pkbf(oacc[dt][nt][2] * rs[nt], oacc[dt][nt][3] * rs[nt]);
          *reinterpret_cast<uint2*>(sv + n * 64 + ((dt * 32 + lh * 8) ^ swq)) = w;
        }
      }
    }
    __syncthreads();   // all heads' O tiles in place for proj

    // ---- Phase 5: proj GEMM + bias, fp32 store (wp transient; O from s_vT) ----
    {
      bf16x8 wp[4][2];
      #pragma unroll
      for (int kk = 0; kk < 4; ++kk)
        #pragma unroll
        for (int ft = 0; ft < 2; ++ft)
          wp[kk][ft] = *reinterpret_cast<const bf16x8*>(
              wproj + (size_t)(h * 32 + ft * 16 + l15) * 128 + kk * 32 + lh * 8);
      floatx4 pacc[4][2];
      #pragma unroll
      for (int mt = 0; mt < 4; ++mt) { pacc[mt][0] = zf4; pacc[mt][1] = zf4; }
      #pragma unroll
      for (int kk = 0; kk < 4; ++kk) {
        bf16x8 of[4];
        #pragma unroll
        for (int mt = 0; mt < 4; ++mt)
          of[mt] = *reinterpret_cast<const bf16x8*>(
              s_vT[kk] + (mt * 16 + l15) * 64 + ((lh * 16) ^ swq));
        #pragma unroll
        for (int ft = 0; ft < 2; ++ft)
          #pragma unroll
          for (int mt = 0; mt < 4; ++mt)
            pacc[mt][ft] = __builtin_amdgcn_mfma_f32_16x16x32_bf16(of[mt], wp[kk][ft], pacc[mt][ft], 0, 0, 0);
      }
      float* ob = out + b * 8192;
      #pragma unroll
      for (int mt = 0; mt < 4; ++mt)
        #pragma unroll
        for (int r = 0; r < 4; ++r) {
          int n = mt * 16 + lh * 4 + r;
          ob[n * 128 + h * 32 + l15]      = pacc[mt][0][r] + pb0;
          ob[n * 128 + h * 32 + 16 + l15] = pacc[mt][1][r] + pb1;
        }
    }
  }
}

extern "C" void kernel_launch(void* const* d_in, const int* in_sizes, int n_in,
                              void* d_out, int out_size, void* d_ws, size_t ws_size,
                              hipStream_t stream)
{
  const float* x    = (const float*)d_in[0];
  const float* mask = (const float*)d_in[1];
  const float* qkvw = (const float*)d_in[2];
  const float* qb   = (const float*)d_in[3];
  const float* vb   = (const float*)d_in[4];
  const float* ls   = (const float*)d_in[5];
  const float* w1   = (const float*)d_in[6];
  const float* b1   = (const float*)d_in[7];
  const float* w2   = (const float*)d_in[8];
  const float* pw   = (const float*)d_in[9];
  const float* pb   = (const float*)d_in[10];
  float* out = (float*)d_out;
  char* ws = (char*)d_ws;

  unsigned short* wsQ = (unsigned short*)ws;   // qkv bf16 + proj bf16
  float* wsBias  = (float*)(ws + WS_BIAS);
  float* wsScale = (float*)(ws + WS_SCALE);
  float* wsTbl   = (float*)(ws + WS_TBL);
  unsigned short* wsE = (unsigned short*)(ws + WS_ETAB);

  hipLaunchKernelGGL(k_prep_weights, dim3(64), dim3(256), 0, stream, qkvw, pw, ls, wsQ, wsScale);
  hipLaunchKernelGGL(k_cpb_table, dim3(225), dim3(256), 0, stream, w1, b1, w2, wsTbl);
  hipLaunchKernelGGL(k_cpb_bias, dim3(64), dim3(256), 0, stream, wsTbl, wsBias);
  hipLaunchKernelGGL(k_exp_table, dim3(4096), dim3(256), 0, stream, wsBias, mask, wsE);
  hipLaunchKernelGGL(k_wmsa, dim3(4096), dim3(256), 0, stream, x,
                     wsQ, wsQ + 49152, qb, vb, wsE, wsScale, pb, out);
}

// Round 19
// 247.659 us; speedup vs baseline: 1.1979x; 1.1016x over previous
//
#include <hip/hip_runtime.h>

typedef __attribute__((ext_vector_type(8))) __bf16 bf16x8;
typedef __attribute__((ext_vector_type(4))) float floatx4;

#define WS_BIAS  131072   // 16384 f32 : cpb bias [h][n][m]
#define WS_SCALE 196608   // 4 f32     : exp(min(logit_scale, log 100))
#define WS_TBL   196640   // 900 f32   : cpb table (225 x 4)
#define WS_ETAB  262144   // 4.19M bf16: E[wm][h][n][m] = exp(bias+mask), 8 MB

static __device__ __forceinline__ unsigned short f2bf_u(float f) {
  union { __bf16 b; unsigned short u; } cv; cv.b = (__bf16)f; return cv.u;
}
static __device__ __forceinline__ unsigned pkbf(float lo, float hi) {
  union { __bf16 b[2]; unsigned u; } cv; cv.b[0] = (__bf16)lo; cv.b[1] = (__bf16)hi; return cv.u;
}
static __device__ __forceinline__ float bfu_lo(unsigned u) { return __uint_as_float(u << 16); }
static __device__ __forceinline__ float bfu_hi(unsigned u) { return __uint_as_float(u & 0xffff0000u); }

// ---- prep: fp32 weights -> bf16 in ws; logit scale ----
__global__ void k_prep_weights(const float* __restrict__ qkv_w,
                               const float* __restrict__ proj_w,
                               const float* __restrict__ logit_scale,
                               unsigned short* __restrict__ wsQ,
                               float* __restrict__ wsScale)
{
  int t = blockIdx.x * 256 + threadIdx.x;   // 0..16383
  int i4 = t * 4;
  float4 v;
  if (i4 < 49152) v = *reinterpret_cast<const float4*>(qkv_w + i4);
  else            v = *reinterpret_cast<const float4*>(proj_w + (i4 - 49152));
  ushort4 pk;
  pk.x = f2bf_u(v.x); pk.y = f2bf_u(v.y); pk.z = f2bf_u(v.z); pk.w = f2bf_u(v.w);
  *reinterpret_cast<ushort4*>(wsQ + i4) = pk;
  if (t < 4) wsScale[t] = expf(fminf(logit_scale[t], 4.6051702f));
}

// ---- prep: CPB MLP table (225 x 4), one block per table row ----
__global__ void k_cpb_table(const float* __restrict__ w1, const float* __restrict__ b1,
                            const float* __restrict__ w2, float* __restrict__ tbl)
{
  __shared__ float red[256][4];
  int t = blockIdx.x;                  // 0..224
  int i = t / 15, j = t % 15;
  float c0 = 8.f * (float)(i - 7) / 7.f;
  float c1 = 8.f * (float)(j - 7) / 7.f;
  c0 = copysignf(log2f(fabsf(c0) + 1.f) / 3.f, c0);
  c1 = copysignf(log2f(fabsf(c1) + 1.f) / 3.f, c1);
  float a0 = 0.f, a1 = 0.f, a2 = 0.f, a3 = 0.f;
  for (int k = threadIdx.x; k < 512; k += 256) {
    float hd = fmaxf(c0 * w1[2*k] + c1 * w1[2*k+1] + b1[k], 0.f);
    a0 += hd * w2[k]; a1 += hd * w2[512+k]; a2 += hd * w2[1024+k]; a3 += hd * w2[1536+k];
  }
  red[threadIdx.x][0]=a0; red[threadIdx.x][1]=a1; red[threadIdx.x][2]=a2; red[threadIdx.x][3]=a3;
  __syncthreads();
  for (int s = 128; s > 0; s >>= 1) {
    if (threadIdx.x < (unsigned)s) {
      red[threadIdx.x][0] += red[threadIdx.x+s][0];
      red[threadIdx.x][1] += red[threadIdx.x+s][1];
      red[threadIdx.x][2] += red[threadIdx.x+s][2];
      red[threadIdx.x][3] += red[threadIdx.x+s][3];
    }
    __syncthreads();
  }
  if (threadIdx.x < 4) tbl[t*4 + threadIdx.x] = red[0][threadIdx.x];
}

// ---- prep: bias[h][n][m] = 16*sigmoid(tbl[rel(n,m)][h]) ----
__global__ void k_cpb_bias(const float* __restrict__ tbl, float* __restrict__ biasT)
{
  int idx = blockIdx.x * 256 + threadIdx.x;   // 0..16383
  int hh = idx >> 12, n = (idx >> 6) & 63, m = idx & 63;
  int rel = ((n >> 3) - (m >> 3) + 7) * 15 + ((n & 7) - (m & 7) + 7);
  float bv = tbl[rel * 4 + hh];
  biasT[idx] = 16.f / (1.f + expf(-bv));
}

// ---- prep: E[wm][h][n][m] = exp(bias+mask) in bf16 (8 MB) ----
__global__ void k_exp_table(const float* __restrict__ biasT, const float* __restrict__ mask,
                            unsigned short* __restrict__ E)
{
  int idx4 = (blockIdx.x * 256 + threadIdx.x) * 4;
  int wm  = idx4 >> 14;
  int rem = idx4 & 16383;
  int hh  = rem >> 12;
  int nm  = rem & 4095;
  float4 mv = *reinterpret_cast<const float4*>(mask + (wm << 12) + nm);
  float4 bv = *reinterpret_cast<const float4*>(biasT + (hh << 12) + nm);
  ushort4 o;
  o.x = f2bf_u(expf(bv.x + mv.x));
  o.y = f2bf_u(expf(bv.y + mv.y));
  o.z = f2bf_u(expf(bv.z + mv.z));
  o.w = f2bf_u(expf(bv.w + mv.w));
  *reinterpret_cast<ushort4*>(E + idx4) = o;
}

// ---- main fused kernel: R16 exact (best measured: 249us) ----
// Paired windows (blk, blk+4096: same mask id -> E frags hoisted per block),
// TRANSIENT weight registers: each sub-GEMM (v / q / k / proj) loads its 8
// weight frags (32 regs) just before use and lets them die -- keeps the
// arch-VGPR floor low so MFMA accumulators live in arch VGPRs (no
// v_accvgpr move tax) and nothing spills (WRITE==output 262MB exactly).
// R17 (merged qk GEMM, VGPR 128) and R18 (O via s_vT, fewer barriers) both
// regressed -- register pressure and wave-serialized LDS access govern, not
// instruction count or barrier count.
__global__ __launch_bounds__(256, 2) void k_wmsa(
    const float* __restrict__ x,
    const unsigned short* __restrict__ wqkv, const unsigned short* __restrict__ wproj,
    const float* __restrict__ q_bias, const float* __restrict__ v_bias,
    const unsigned short* __restrict__ Etab, const float* __restrict__ scale4,
    const float* __restrict__ proj_b, float* __restrict__ out)
{
  __shared__ char s_x[64 * 256];     // 16KB: x bf16 swizzled; later O [n][c] bf16
  __shared__ char s_qk[4][8192];     // 32KB: per head q[64][32]+k[64][32]; later P[64][64]
  __shared__ char s_vT[4][4096];     // 16KB: per head vT[32][64] bf16, swz (d&7)<<4

  const int blk  = blockIdx.x;
  const int tid  = threadIdx.x;
  const int lane = tid & 63;
  const int h    = tid >> 6;
  const int l15  = lane & 15;
  const int lh   = lane >> 4;
  const int swq  = ((l15 ^ (l15 >> 2)) & 3) << 4;  // q/k row swizzle (row = 16t+l15)
  const int swp  = (l15 & 7) << 4;                 // P / vT row swizzle
  const floatx4 zf4 = {0.f, 0.f, 0.f, 0.f};

  floatx4 qb0 = *reinterpret_cast<const floatx4*>(q_bias + h * 32 + lh * 4);
  floatx4 qb1 = *reinterpret_cast<const floatx4*>(q_bias + h * 32 + 16 + lh * 4);
  const float vb0 = v_bias[h * 32 + l15], vb1 = v_bias[h * 32 + 16 + l15];
  const float sc  = scale4[h] * 1.44269504f;   // fold log2e into q scale
  const float pb0 = proj_b[h * 32 + l15], pb1 = proj_b[h * 32 + 16 + l15];
  const unsigned short* Eh = Etab + ((size_t)((blk & 255) * 4 + h)) * 4096;

  // ---- E-table frags: per-block constant, hoisted across both windows ----
  uint2 e[4][4];   // [tn][tm]: 4 bf16 each (n=tn*16+l15, m=tm*16+lh*4..+3)
  #pragma unroll
  for (int tn = 0; tn < 4; ++tn)
    #pragma unroll
    for (int tm = 0; tm < 4; ++tm)
      e[tn][tm] = *reinterpret_cast<const uint2*>(
          Eh + (tn * 16 + l15) * 64 + tm * 16 + lh * 4);

  #pragma unroll
  for (int wi = 0; wi < 2; ++wi) {
    const size_t b = (size_t)blk + (size_t)wi * 4096;

    if (wi) __syncthreads();   // prev proj done reading s_x before restage

    // ---- Phase 0: stage x tile -> bf16 swizzled LDS ----
    {
      const float* xb = x + b * 8192;
      int r = tid >> 2;
      #pragma unroll
      for (int cc = 0; cc < 8; ++cc) {
        int c = (tid & 3) + cc * 4;
        float4 v = reinterpret_cast<const float4*>(xb)[r * 32 + c];
        uint2 w; w.x = pkbf(v.x, v.y); w.y = pkbf(v.z, v.w);
        *reinterpret_cast<uint2*>(s_x + r * 256 + ((c * 8) ^ ((r & 7) << 4))) = w;
      }
    }
    __syncthreads();

    // ---- Phase 1a: v = x @ Wv^T (wv transient) ----
    {
      bf16x8 wv[4][2];
      #pragma unroll
      for (int kk = 0; kk < 4; ++kk)
        #pragma unroll
        for (int ft = 0; ft < 2; ++ft)
          wv[kk][ft] = *reinterpret_cast<const bf16x8*>(
              wqkv + (size_t)(256 + h * 32 + ft * 16 + l15) * 128 + kk * 32 + lh * 8);
      floatx4 vacc[4][2];
      #pragma unroll
      for (int mt = 0; mt < 4; ++mt) { vacc[mt][0] = zf4; vacc[mt][1] = zf4; }
      #pragma unroll
      for (int kk = 0; kk < 4; ++kk) {
        bf16x8 xf[4];
        #pragma unroll
        for (int tt = 0; tt < 4; ++tt) {
          int row = tt * 16 + l15;
          xf[tt] = *reinterpret_cast<const bf16x8*>(
              s_x + row * 256 + (((kk * 32 + lh * 8) * 2) ^ ((row & 7) << 4)));
        }
        #pragma unroll
        for (int ft = 0; ft < 2; ++ft)
          #pragma unroll
          for (int mt = 0; mt < 4; ++mt)
            vacc[mt][ft] = __builtin_amdgcn_mfma_f32_16x16x32_bf16(xf[mt], wv[kk][ft], vacc[mt][ft], 0, 0, 0);
      }
      // v bias; vT[d][m] packed b64 writes (wave-private)
      char* sv = s_vT[h];
      #pragma unroll
      for (int mt = 0; mt < 4; ++mt) {
        #pragma unroll
        for (int ft = 0; ft < 2; ++ft) {
          float vb = ft ? vb1 : vb0;
          int d = ft * 16 + l15;
          uint2 w;
          w.x = pkbf(vacc[mt][ft][0] + vb, vacc[mt][ft][1] + vb);
          w.y = pkbf(vacc[mt][ft][2] + vb, vacc[mt][ft][3] + vb);
          *reinterpret_cast<uint2*>(sv + d * 128 + (((mt * 16 + lh * 4) * 2) ^ swp)) = w;
        }
      }
    }

    // ---- Phase 1b: q^T = Wq @ x^T (wq transient); bias+norm; -> LDS -> qf ----
    bf16x8 qf[4], kf[4];
    {
      bf16x8 wq[4][2];
      #pragma unroll
      for (int kk = 0; kk < 4; ++kk)
        #pragma unroll
        for (int ft = 0; ft < 2; ++ft)
          wq[kk][ft] = *reinterpret_cast<const bf16x8*>(
              wqkv + (size_t)(h * 32 + ft * 16 + l15) * 128 + kk * 32 + lh * 8);
      floatx4 qacc[2][4];
      #pragma unroll
      for (int ff = 0; ff < 2; ++ff)
        #pragma unroll
        for (int tt = 0; tt < 4; ++tt) qacc[ff][tt] = zf4;
      #pragma unroll
      for (int kk = 0; kk < 4; ++kk) {
        bf16x8 xf[4];
        #pragma unroll
        for (int tt = 0; tt < 4; ++tt) {
          int row = tt * 16 + l15;
          xf[tt] = *reinterpret_cast<const bf16x8*>(
              s_x + row * 256 + (((kk * 32 + lh * 8) * 2) ^ ((row & 7) << 4)));
        }
        #pragma unroll
        for (int ff = 0; ff < 2; ++ff)
          #pragma unroll
          for (int tt = 0; tt < 4; ++tt)
            qacc[ff][tt] = __builtin_amdgcn_mfma_f32_16x16x32_bf16(wq[kk][ff], xf[tt], qacc[ff][tt], 0, 0, 0);
      }
      #pragma unroll
      for (int tt = 0; tt < 4; ++tt) {
        #pragma unroll
        for (int r = 0; r < 4; ++r) { qacc[0][tt][r] += qb0[r]; qacc[1][tt][r] += qb1[r]; }
        float sq = 0.f;
        #pragma unroll
        for (int r = 0; r < 4; ++r)
          sq += qacc[0][tt][r] * qacc[0][tt][r] + qacc[1][tt][r] * qacc[1][tt][r];
        sq += __shfl_xor(sq, 16); sq += __shfl_xor(sq, 32);
        float rq = sc / fmaxf(sqrtf(sq), 1e-12f);
        #pragma unroll
        for (int r = 0; r < 4; ++r) { qacc[0][tt][r] *= rq; qacc[1][tt][r] *= rq; }
      }
      char* sq = s_qk[h];
      #pragma unroll
      for (int tt = 0; tt < 4; ++tt) {
        int row = 16 * tt + l15;
        #pragma unroll
        for (int ff = 0; ff < 2; ++ff) {
          uint2 w;
          w.x = pkbf(qacc[ff][tt][0], qacc[ff][tt][1]);
          w.y = pkbf(qacc[ff][tt][2], qacc[ff][tt][3]);
          *reinterpret_cast<uint2*>(sq + row * 64 + ((ff * 32 + lh * 8) ^ swq)) = w;
        }
      }
      #pragma unroll
      for (int tt = 0; tt < 4; ++tt)
        qf[tt] = *reinterpret_cast<const bf16x8*>(sq + (16 * tt + l15) * 64 + ((lh * 16) ^ swq));
    }

    // ---- Phase 1c: k^T = Wk @ x^T (wk transient); norm; -> LDS -> kf ----
    {
      bf16x8 wk[4][2];
      #pragma unroll
      for (int kk = 0; kk < 4; ++kk)
        #pragma unroll
        for (int ft = 0; ft < 2; ++ft)
          wk[kk][ft] = *reinterpret_cast<const bf16x8*>(
              wqkv + (size_t)(128 + h * 32 + ft * 16 + l15) * 128 + kk * 32 + lh * 8);
      floatx4 kacc[2][4];
      #pragma unroll
      for (int ff = 0; ff < 2; ++ff)
        #pragma unroll
        for (int tt = 0; tt < 4; ++tt) kacc[ff][tt] = zf4;
      #pragma unroll
      for (int kk = 0; kk < 4; ++kk) {
        bf16x8 xf[4];
        #pragma unroll
        for (int tt = 0; tt < 4; ++tt) {
          int row = tt * 16 + l15;
          xf[tt] = *reinterpret_cast<const bf16x8*>(
              s_x + row * 256 + (((kk * 32 + lh * 8) * 2) ^ ((row & 7) << 4)));
        }
        #pragma unroll
        for (int ff = 0; ff < 2; ++ff)
          #pragma unroll
          for (int tt = 0; tt < 4; ++tt)
            kacc[ff][tt] = __builtin_amdgcn_mfma_f32_16x16x32_bf16(wk[kk][ff], xf[tt], kacc[ff][tt], 0, 0, 0);
      }
      #pragma unroll
      for (int tt = 0; tt < 4; ++tt) {
        float sk = 0.f;
        #pragma unroll
        for (int r = 0; r < 4; ++r)
          sk += kacc[0][tt][r] * kacc[0][tt][r] + kacc[1][tt][r] * kacc[1][tt][r];
        sk += __shfl_xor(sk, 16); sk += __shfl_xor(sk, 32);
        float rk = 1.f / fmaxf(sqrtf(sk), 1e-12f);
        #pragma unroll
        for (int r = 0; r < 4; ++r) { kacc[0][tt][r] *= rk; kacc[1][tt][r] *= rk; }
      }
      char* sq = s_qk[h];
      #pragma unroll
      for (int tt = 0; tt < 4; ++tt) {
        int row = 16 * tt + l15;
        #pragma unroll
        for (int ff = 0; ff < 2; ++ff) {
          uint2 w;
          w.x = pkbf(kacc[ff][tt][0], kacc[ff][tt][1]);
          w.y = pkbf(kacc[ff][tt][2], kacc[ff][tt][3]);
          *reinterpret_cast<uint2*>(sq + 4096 + row * 64 + ((ff * 32 + lh * 8) ^ swq)) = w;
        }
      }
      #pragma unroll
      for (int tt = 0; tt < 4; ++tt)
        kf[tt] = *reinterpret_cast<const bf16x8*>(
            sq + 4096 + (16 * tt + l15) * 64 + ((lh * 16) ^ swq));
    }

    // ---- Phase 2+3 fused: S^T, exp2*E, col sums, P->LDS ----
    floatx4 rs;
    {
      char* sp = s_qk[h];   // P overwrites q/k (qf/kf already in regs)
      #pragma unroll
      for (int tn = 0; tn < 4; ++tn) {
        floatx4 sacc[4];
        #pragma unroll
        for (int tm = 0; tm < 4; ++tm)
          sacc[tm] = __builtin_amdgcn_mfma_f32_16x16x32_bf16(kf[tm], qf[tn], zf4, 0, 0, 0);
        float sum = 0.f;
        uint2 pw[4];
        #pragma unroll
        for (int tm = 0; tm < 4; ++tm) {
          uint2 eu = e[tn][tm];
          float e0 = exp2f(sacc[tm][0]) * bfu_lo(eu.x);
          float e1 = exp2f(sacc[tm][1]) * bfu_hi(eu.x);
          float e2 = exp2f(sacc[tm][2]) * bfu_lo(eu.y);
          float e3 = exp2f(sacc[tm][3]) * bfu_hi(eu.y);
          sum += (e0 + e1) + (e2 + e3);
          pw[tm].x = pkbf(e0, e1); pw[tm].y = pkbf(e2, e3);
        }
        sum += __shfl_xor(sum, 16); sum += __shfl_xor(sum, 32);
        rs[tn] = 1.f / sum;
        int prow = 16 * tn + l15;
        #pragma unroll
        for (int tm = 0; tm < 4; ++tm)
          *reinterpret_cast<uint2*>(sp + prow * 128 + ((tm * 32 + lh * 8) ^ swp)) = pw[tm];
      }
    }

    // ---- Phase 4: O^T = V^T @ P^T ----
    floatx4 oacc[2][4];
    #pragma unroll
    for (int dt = 0; dt < 2; ++dt)
      #pragma unroll
      for (int nt = 0; nt < 4; ++nt) oacc[dt][nt] = zf4;
    {
      const char* sv = s_vT[h];
      const char* sp = s_qk[h];
      #pragma unroll
      for (int kk = 0; kk < 2; ++kk) {
        bf16x8 vf[2];
        #pragma unroll
        for (int dt = 0; dt < 2; ++dt)
          vf[dt] = *reinterpret_cast<const bf16x8*>(
              sv + (dt * 16 + l15) * 128 + ((kk * 64 + lh * 16) ^ swp));
        #pragma unroll
        for (int nt = 0; nt < 4; ++nt) {
          bf16x8 pf = *reinterpret_cast<const bf16x8*>(
              sp + (nt * 16 + l15) * 128 + ((kk * 64 + lh * 16) ^ swp));
          #pragma unroll
          for (int dt = 0; dt < 2; ++dt)
            oacc[dt][nt] = __builtin_amdgcn_mfma_f32_16x16x32_bf16(vf[dt], pf, oacc[dt][nt], 0, 0, 0);
        }
      }
    }
    __syncthreads();   // all waves done reading s_x before O overwrites it

    // O (scaled by 1/rowsum) -> s_x as [n][c] bf16
    #pragma unroll
    for (int dt = 0; dt < 2; ++dt) {
      #pragma unroll
      for (int nt = 0; nt < 4; ++nt) {
        int n = nt * 16 + l15;
        uint2 w;
        w.x = pkbf(oacc[dt][nt][0] * rs[nt], oacc[dt][nt][1] * rs[nt]);
        w.y = pkbf(oacc[dt][nt][2] * rs[nt], oacc[dt][nt][3] * rs[nt]);
        *reinterpret_cast<uint2*>(
            s_x + n * 256 + (((h * 32 + dt * 16 + lh * 4) * 2) ^ ((n & 7) << 4))) = w;
      }
    }
    __syncthreads();

    // ---- Phase 5: proj GEMM + bias, fp32 store (wp transient) ----
    {
      bf16x8 wp[4][2];
      #pragma unroll
      for (int kk = 0; kk < 4; ++kk)
        #pragma unroll
        for (int ft = 0; ft < 2; ++ft)
          wp[kk][ft] = *reinterpret_cast<const bf16x8*>(
              wproj + (size_t)(h * 32 + ft * 16 + l15) * 128 + kk * 32 + lh * 8);
      floatx4 pacc[4][2];
      #pragma unroll
      for (int mt = 0; mt < 4; ++mt) { pacc[mt][0] = zf4; pacc[mt][1] = zf4; }
      #pragma unroll
      for (int kk = 0; kk < 4; ++kk) {
        bf16x8 of[4];
        #pragma unroll
        for (int mt = 0; mt < 4; ++mt) {
          int row = mt * 16 + l15;
          of[mt] = *reinterpret_cast<const bf16x8*>(
              s_x + row * 256 + (((kk * 32 + lh * 8) * 2) ^ ((row & 7) << 4)));
        }
        #pragma unroll
        for (int ft = 0; ft < 2; ++ft)
          #pragma unroll
          for (int mt = 0; mt < 4; ++mt)
            pacc[mt][ft] = __builtin_amdgcn_mfma_f32_16x16x32_bf16(of[mt], wp[kk][ft], pacc[mt][ft], 0, 0, 0);
      }
      float* ob = out + b * 8192;
      #pragma unroll
      for (int mt = 0; mt < 4; ++mt)
        #pragma unroll
        for (int r = 0; r < 4; ++r) {
          int n = mt * 16 + lh * 4 + r;
          ob[n * 128 + h * 32 + l15]      = pacc[mt][0][r] + pb0;
          ob[n * 128 + h * 32 + 16 + l15] = pacc[mt][1][r] + pb1;
        }
    }
  }
}

extern "C" void kernel_launch(void* const* d_in, const int* in_sizes, int n_in,
                              void* d_out, int out_size, void* d_ws, size_t ws_size,
                              hipStream_t stream)
{
  const float* x    = (const float*)d_in[0];
  const float* mask = (const float*)d_in[1];
  const float* qkvw = (const float*)d_in[2];
  const float* qb   = (const float*)d_in[3];
  const float* vb   = (const float*)d_in[4];
  const float* ls   = (const float*)d_in[5];
  const float* w1   = (const float*)d_in[6];
  const float* b1   = (const float*)d_in[7];
  const float* w2   = (const float*)d_in[8];
  const float* pw   = (const float*)d_in[9];
  const float* pb   = (const float*)d_in[10];
  float* out = (float*)d_out;
  char* ws = (char*)d_ws;

  unsigned short* wsQ = (unsigned short*)ws;   // qkv bf16 + proj bf16
  float* wsBias  = (float*)(ws + WS_BIAS);
  float* wsScale = (float*)(ws + WS_SCALE);
  float* wsTbl   = (float*)(ws + WS_TBL);
  unsigned short* wsE = (unsigned short*)(ws + WS_ETAB);

  hipLaunchKernelGGL(k_prep_weights, dim3(64), dim3(256), 0, stream, qkvw, pw, ls, wsQ, wsScale);
  hipLaunchKernelGGL(k_cpb_table, dim3(225), dim3(256), 0, stream, w1, b1, w2, wsTbl);
  hipLaunchKernelGGL(k_cpb_bias, dim3(64), dim3(256), 0, stream, wsTbl, wsBias);
  hipLaunchKernelGGL(k_exp_table, dim3(4096), dim3(256), 0, stream, wsBias, mask, wsE);
  hipLaunchKernelGGL(k_wmsa, dim3(4096), dim3(256), 0, stream, x,
                     wsQ, wsQ + 49152, qb, vb, wsE, wsScale, pb, out);
}